// Round 7
// baseline (190.976 us; speedup 1.0000x reference)
//
#include <hip/hip_runtime.h>
#include <hip/hip_bf16.h>
#include <math.h>

// Problem constants: B=2, T=2048, M=1024, H=8, D=128
#define B_  2
#define T_  2048
#define M_  1024
#define H_  8
#define D_  128
#define NROW (B_ * T_)          // 4096
#define HD  (H_ * D_)           // 1024

#define NORM_EPS 1e-6f
#define QK_MULT  0.08838834764831845f   // sqrt(1/128)
#define LN_BASE_64 0.14391156510f       // ln(10000)/64

typedef short bf16x8  __attribute__((ext_vector_type(8)));    // 8 bf16 = 4 VGPRs
typedef float f32x4   __attribute__((ext_vector_type(4)));
typedef float f32x16  __attribute__((ext_vector_type(16)));
typedef unsigned int uint32x2 __attribute__((ext_vector_type(2)));

static __device__ __forceinline__ unsigned short f2bf(float f) {
    union { __hip_bfloat16 h; unsigned short u; } cv;
    cv.h = __float2bfloat16(f);
    return cv.u;
}
static __device__ __forceinline__ unsigned int pk2bf(float a, float b) {
    return ((unsigned int)f2bf(b) << 16) | f2bf(a);
}

// async global->LDS, 16 bytes per lane. LDS dest = wave-uniform base + lane*16.
static __device__ __forceinline__ void gload_lds16(const unsigned short* g,
                                                   unsigned short* l) {
    __builtin_amdgcn_global_load_lds(
        (const __attribute__((address_space(1))) void*)g,
        (__attribute__((address_space(3))) void*)l, 16, 0, 0);
}

// ---------------------------------------------------------------------------
// prep: z<4 -> transpose+cast weight z (out[n][k]=bf16(in[k][n]));
//       z==4 -> linear cast of x to bf16.
// ---------------------------------------------------------------------------
__global__ __launch_bounds__(256) void prep(const float* __restrict__ x,
                                            const float* __restrict__ w0,
                                            const float* __restrict__ w1,
                                            const float* __restrict__ w2,
                                            const float* __restrict__ w3,
                                            unsigned short* __restrict__ xb,
                                            unsigned short* __restrict__ wqkvT,
                                            unsigned short* __restrict__ woT)
{
    __shared__ float t[32][33];
    const int z = blockIdx.z;
    if (z == 4) {
        const size_t base = ((size_t)blockIdx.y * 32 + blockIdx.x) * 4096;
        #pragma unroll
        for (int it = 0; it < 4; ++it) {
            const size_t i = base + it * 1024 + threadIdx.x * 4;
            const float4 v = *(const float4*)(x + i);
            ushort4 o;
            o.x = f2bf(v.x); o.y = f2bf(v.y); o.z = f2bf(v.z); o.w = f2bf(v.w);
            *(ushort4*)(xb + i) = o;
        }
        return;
    }
    const float* in = z == 0 ? w0 : (z == 1 ? w1 : (z == 2 ? w2 : w3));
    unsigned short* out = z < 3 ? (wqkvT + (size_t)z * 1024 * 1024) : woT;

    const int tx = threadIdx.x & 31;
    const int ty = threadIdx.x >> 5;
    const int n0 = blockIdx.x * 32;
    const int k0 = blockIdx.y * 32;
    #pragma unroll
    for (int r = 0; r < 4; ++r)
        t[ty + r * 8][tx] = in[(size_t)(k0 + ty + r * 8) * 1024 + n0 + tx];
    __syncthreads();
    #pragma unroll
    for (int r = 0; r < 4; ++r)
        out[(size_t)(n0 + ty + r * 8) * 1024 + k0 + tx] = f2bf(t[tx][ty + r * 8]);
}

// ---------------------------------------------------------------------------
// QKV GEMM: C = A[4096x1024] * Bt[3072x1024]^T. 128x128 tile, BK=32,
// async double-buffered global_load_lds staging, 3 blocks/CU. V epilogue
// transposes via LDS so vt is written in contiguous 256-B rows.
// ---------------------------------------------------------------------------
__global__ __launch_bounds__(256) void gemm_qkv(const unsigned short* __restrict__ A,
                                                const unsigned short* __restrict__ Bt,
                                                unsigned short* __restrict__ oq,
                                                unsigned short* __restrict__ ok,
                                                unsigned short* __restrict__ vt)
{
    __shared__ __align__(16) unsigned short smem[17408];   // 34 KB
    #define AsQ(buf) (smem + (buf) * 4096)
    #define BsQ(buf) (smem + 8192 + (buf) * 4096)

    const int tid  = threadIdx.x;
    const int lane = tid & 63;
    const int w    = tid >> 6;          // wave = row band (32 rows)
    const int g    = lane >> 4;
    const int lc   = lane & 15;

    const int m0 = blockIdx.y * 128;
    const int n0 = blockIdx.x * 128;

    const unsigned short* aBase = A  + (size_t)m0 * 1024;
    const unsigned short* bBase = Bt + (size_t)n0 * 1024;

    int dstOff[2];
    size_t srcOff[2];
    #pragma unroll
    for (int it = 0; it < 2; ++it) {
        const int u  = tid + it * 256;      // 0..511
        const int r2 = u >> 2;              // tile row
        const int sg = (u & 3) ^ (r2 & 3);  // src segment (XOR swizzle)
        dstOff[it] = u * 8;
        srcOff[it] = (size_t)r2 * 1024 + sg * 8;
    }

    f32x4 acc[2][8];
    #pragma unroll
    for (int i = 0; i < 2; ++i)
        #pragma unroll
        for (int j = 0; j < 8; ++j)
            acc[i][j] = (f32x4){0.f, 0.f, 0.f, 0.f};

    #pragma unroll
    for (int it = 0; it < 2; ++it) {
        gload_lds16(aBase + srcOff[it], AsQ(0) + dstOff[it]);
        gload_lds16(bBase + srcOff[it], BsQ(0) + dstOff[it]);
    }

    for (int kt = 0; kt < 32; ++kt) {
        const int cur = kt & 1;
        __syncthreads();                      // tile kt ready; buf^1 free

        if (kt < 31) {                        // async-prefetch next K-tile
            const int k0n = (kt + 1) * 32;
            #pragma unroll
            for (int it = 0; it < 2; ++it) {
                gload_lds16(aBase + srcOff[it] + k0n, AsQ(cur ^ 1) + dstOff[it]);
                gload_lds16(bBase + srcOff[it] + k0n, BsQ(cur ^ 1) + dstOff[it]);
            }
        }

        const int sw = (g ^ (lc & 3)) << 3;
        bf16x8 af[2], bfr[8];
        #pragma unroll
        for (int i = 0; i < 2; ++i)
            af[i] = *(const bf16x8*)&AsQ(cur)[(w * 32 + i * 16 + lc) * 32 + sw];
        #pragma unroll
        for (int j = 0; j < 8; ++j)
            bfr[j] = *(const bf16x8*)&BsQ(cur)[(j * 16 + lc) * 32 + sw];

        #pragma unroll
        for (int i = 0; i < 2; ++i)
            #pragma unroll
            for (int j = 0; j < 8; ++j)
                acc[i][j] = __builtin_amdgcn_mfma_f32_16x16x32_bf16(af[i], bfr[j], acc[i][j], 0, 0, 0);
    }

    const int which = n0 >> 10;
    const int ncol0 = n0 & 1023;            // head-aligned (tile = one head)
    if (which < 2) {
        // ---- fused RMSNorm + RoPE + sqrt(qk_scale) for q / k ----
        unsigned short* outp = which == 0 ? oq : ok;
        float freq[4];
        #pragma unroll
        for (int j = 0; j < 4; ++j)
            freq[j] = __expf(-(float)(j * 16 + lc) * LN_BASE_64);

        #pragma unroll
        for (int i = 0; i < 2; ++i)
            #pragma unroll
            for (int r = 0; r < 4; ++r) {
                float s = 0.f;
                #pragma unroll
                for (int j = 0; j < 8; ++j) s += acc[i][j][r] * acc[i][j][r];
                #pragma unroll
                for (int off = 1; off < 16; off <<= 1) s += __shfl_xor(s, off);
                const float rms = rsqrtf(s * (1.0f / 128.0f) + NORM_EPS) * QK_MULT;

                const int trow = m0 + w * 32 + i * 16 + g * 4 + r;
                const float tpos = (float)(trow & (T_ - 1));
                unsigned short* op = outp + (size_t)trow * 1024 + ncol0;
                #pragma unroll
                for (int j = 0; j < 4; ++j) {
                    float sn, cs;
                    __sincosf(tpos * freq[j], &sn, &cs);
                    const float e = acc[i][j][r] * rms;       // even half
                    const float o = acc[i][j + 4][r] * rms;   // odd half (+64)
                    op[j * 16 + lc]      = f2bf(e * cs - o * sn);
                    op[j * 16 + lc + 64] = f2bf(e * sn + o * cs);
                }
            }
    } else {
        // V: transpose in LDS, then dump contiguous 256-B rows ->
        // vt[(b*8+h)*128 + d][t]. Full-line writes, no write-allocate RMW.
        const int b2 = m0 >> 11;
        const int hh = ncol0 >> 7;
        const int PAD = 136;                 // 272 B rows: 16-B aligned, odd*16
        __syncthreads();                     // staging reads done; reuse smem
        #pragma unroll
        for (int i = 0; i < 2; ++i) {
            const int t0 = w * 32 + i * 16 + g * 4;
            #pragma unroll
            for (int j = 0; j < 8; ++j) {
                uint2 val;
                val.x = pk2bf(acc[i][j][0], acc[i][j][1]);
                val.y = pk2bf(acc[i][j][2], acc[i][j][3]);
                *(uint2*)&smem[(j * 16 + lc) * PAD + t0] = val;
            }
        }
        __syncthreads();
        const int row  = tid >> 1;           // d (0..127)
        const int half = tid & 1;            // t half (64 shorts)
        const unsigned short* src = &smem[row * PAD + half * 64];
        unsigned short* dst = vt + ((size_t)(b2 * 8 + hh) * 128 + row) * T_
                                 + (m0 & 2047) + half * 64;
        #pragma unroll
        for (int it2 = 0; it2 < 8; ++it2)
            *(uint4*)(dst + it2 * 8) = *(const uint4*)(src + it2 * 8);
    }
    #undef AsQ
    #undef BsQ
}

// ---------------------------------------------------------------------------
// Output projection: C[4096x1024] fp32 = A * Bt^T. 128x64 tile (512 blocks,
// 3/CU, all resident), BK=64, async double-buffered staging + XOR swizzle.
// 2x2 waves of 64x32.
// ---------------------------------------------------------------------------
__global__ __launch_bounds__(256) void gemm_out(const unsigned short* __restrict__ A,
                                                const unsigned short* __restrict__ Bt,
                                                float* __restrict__ cf)
{
    __shared__ unsigned short As[2][128 * 64];   // 2 x 16 KB
    __shared__ unsigned short Bs[2][64 * 64];    // 2 x 8 KB  (48 KB total)

    const int tid  = threadIdx.x;
    const int lane = tid & 63;
    const int w    = tid >> 6;
    const int g    = lane >> 4;
    const int lc   = lane & 15;
    const int wm   = w >> 1;
    const int wn   = w & 1;

    const int m0 = blockIdx.y * 128;
    const int n0 = blockIdx.x * 64;

    const unsigned short* aBase = A  + (size_t)m0 * 1024;
    const unsigned short* bBase = Bt + (size_t)n0 * 1024;

    int dstA[4], dstB[2];
    size_t srcA[4], srcB[2];
    #pragma unroll
    for (int it = 0; it < 4; ++it) {
        const int u  = tid + it * 256;
        const int r2 = u >> 3;
        const int sg = (u & 7) ^ (r2 & 7);
        dstA[it] = u * 8;
        srcA[it] = (size_t)r2 * 1024 + sg * 8;
    }
    #pragma unroll
    for (int it = 0; it < 2; ++it) {
        const int u  = tid + it * 256;
        const int r2 = u >> 3;
        const int sg = (u & 7) ^ (r2 & 7);
        dstB[it] = u * 8;
        srcB[it] = (size_t)r2 * 1024 + sg * 8;
    }

    f32x4 acc[4][2];
    #pragma unroll
    for (int i = 0; i < 4; ++i)
        #pragma unroll
        for (int j = 0; j < 2; ++j)
            acc[i][j] = (f32x4){0.f, 0.f, 0.f, 0.f};

    #pragma unroll
    for (int it = 0; it < 4; ++it)
        gload_lds16(aBase + srcA[it], &As[0][dstA[it]]);
    #pragma unroll
    for (int it = 0; it < 2; ++it)
        gload_lds16(bBase + srcB[it], &Bs[0][dstB[it]]);

    for (int kt = 0; kt < 16; ++kt) {
        const int cur = kt & 1;
        __syncthreads();

        if (kt < 15) {
            const int k0n = (kt + 1) * 64;
            #pragma unroll
            for (int it = 0; it < 4; ++it)
                gload_lds16(aBase + srcA[it] + k0n, &As[cur ^ 1][dstA[it]]);
            #pragma unroll
            for (int it = 0; it < 2; ++it)
                gload_lds16(bBase + srcB[it] + k0n, &Bs[cur ^ 1][dstB[it]]);
        }

        #pragma unroll
        for (int dc = 0; dc < 2; ++dc) {
            const int sw = ((dc * 4 + g) ^ (lc & 7)) << 3;
            bf16x8 af[4], bfr[2];
            #pragma unroll
            for (int i = 0; i < 4; ++i)
                af[i] = *(const bf16x8*)&As[cur][(wm * 64 + i * 16 + lc) * 64 + sw];
            #pragma unroll
            for (int j = 0; j < 2; ++j)
                bfr[j] = *(const bf16x8*)&Bs[cur][(wn * 32 + j * 16 + lc) * 64 + sw];

            #pragma unroll
            for (int i = 0; i < 4; ++i)
                #pragma unroll
                for (int j = 0; j < 2; ++j)
                    acc[i][j] = __builtin_amdgcn_mfma_f32_16x16x32_bf16(af[i], bfr[j], acc[i][j], 0, 0, 0);
        }
    }

    #pragma unroll
    for (int i = 0; i < 4; ++i) {
        const int mrow = m0 + wm * 64 + i * 16 + g * 4;
        #pragma unroll
        for (int j = 0; j < 2; ++j) {
            const int nc = n0 + wn * 32 + j * 16 + lc;
            #pragma unroll
            for (int r = 0; r < 4; ++r)
                cf[(size_t)(mrow + r) * 1024 + nc] = acc[i][j][r];
        }
    }
}

// ---------------------------------------------------------------------------
// Flash attention v7: IN-BLOCK SEQUENTIAL PAIRING + deep pipeline.
// Lessons R1/R4/R5/R6: per-CU completion is max() over co-resident blocks
// (pairing across blocks never balanced anything); cross-block merge is
// forbidden (dispatch order, G16); 1-block-per-CU grids re-create the
// triangular imbalance. The only safe balance: each block owns q-tiles
// (qt, 31-qt) OF THE SAME bh and runs them SEQUENTIALLY -> exactly 33
// KV-iterations for EVERY block, and the K/V staging stream is continuous
// across the tile switch (same source!).
// 256 blocks x 256 thr (R3's proven 4-wave interior: wj x wq2), 1/CU.
// Pipeline: 4-buffer rotation (128 KB LDS), counted vmcnt(16) -> stage u
// is waited 3 full iterations after issue (~3000 cy lead > ~2000 cy RT,
// DMA fully hidden; R6's 1-iter lead was too shallow). Tail keeps the
// count uniform with harmless dummy stages into never-read buffers.
// Tile A's mid-loop epilogue reuses the just-consumed buffer (u&3) as f32
// scratch -- barrier-protected on both sides; in-flight DMA targets the
// other three buffers.
// XCD locality: bid&7 = XCD (round-robin dispatch heuristic), bh =
// (bid&7) + 8*(s&1) -> each XCD touches only 2 bh = 2 MB K/V, L2-resident
// (fixes R6's 55 MB FETCH: all-16-bh-per-XCD thrashed the 4 MB L2).
// ---------------------------------------------------------------------------
__global__ __launch_bounds__(256) void flash_attn(const unsigned short* __restrict__ qb,
                                                  const unsigned short* __restrict__ kb,
                                                  const unsigned short* __restrict__ vt,
                                                  unsigned short* __restrict__ o)
{
    // 4 x (K 16KB | V 16KB) = 128 KB + 256 B lscr
    __shared__ __align__(16) unsigned short smem[4 * 16384 + 128];
    float* lscr = (float*)(smem + 4 * 16384);      // 64 f32

    const int tid  = threadIdx.x;
    const int lane = tid & 63;
    const int w    = tid >> 6;
    const int wj   = w >> 1;            // j-half
    const int wq2  = w & 1;             // q-half
    const int qcol = lane & 31;
    const int hi   = lane >> 5;         // half-wave

    // XCD-aware unit mapping: 256 blocks = 16 bh x 16 pairs
    const int bid = blockIdx.x;
    const int s   = bid >> 3;
    const int bh  = (bid & 7) + 8 * (s & 1);
    const int qtA = s >> 1;             // 0..15
    const int qtB = 31 - qtA;           // 16..31
    const int h   = bh & (H_ - 1);
    const int b   = bh >> 3;

    const size_t bhbase  = (size_t)b * T_ * HD + (size_t)h * 128;   // q,k,o
    const size_t bhvbase = (size_t)bh * 128 * T_;                   // vt

    int mI[4];
    size_t srcKoff[4], srcVoff[4];
    #pragma unroll
    for (int it = 0; it < 4; ++it) {
        const int m = (w * 4 + it) * 64 + lane;     // 0..1023
        mI[it] = m;
        const int jK = m >> 4, cK = (m & 15) ^ (jK & 15);
        srcKoff[it] = (size_t)jK * 1024 + cK * 8;
        const int dV = m >> 3, cV = (m & 7) ^ (dV & 7);
        srcVoff[it] = (size_t)dV * T_ + cV * 8;
    }
    const unsigned short* kgb = kb + bhbase;
    const unsigned short* vgb = vt + bhvbase;

    // stage KV unit js (0..32 continuous stream; js>qtA -> tile B jt js-qtA-1)
#define SRCU(s_) ((s_) > qtA ? (s_) - qtA - 1 : (s_))
#define STAGE(js_, bf_) {                                                    \
        const size_t jo = (size_t)(js_) * 64;                                \
        unsigned short* Kd = smem + (bf_) * 16384;                           \
        unsigned short* Vd = Kd + 8192;                                      \
        _Pragma("unroll")                                                    \
        for (int it = 0; it < 4; ++it)                                       \
            gload_lds16(kgb + jo * 1024 + srcKoff[it], &Kd[mI[it] * 8]);     \
        _Pragma("unroll")                                                    \
        for (int it = 0; it < 4; ++it)                                       \
            gload_lds16(vgb + jo + srcVoff[it], &Vd[mI[it] * 8]);            \
    }

    // Q frags for tile A
    bf16x8 qf[8];
    {
        const unsigned short* qp = qb + bhbase
            + (size_t)(qtA * 64 + wq2 * 32 + qcol) * 1024 + hi * 8;
        #pragma unroll
        for (int ks = 0; ks < 8; ++ks)
            qf[ks] = *(const bf16x8*)(qp + ks * 16);
    }

    float lsum = 0.f;
    f32x16 otacc[4];
    #pragma unroll
    for (int dch = 0; dch < 4; ++dch)
        #pragma unroll
        for (int r = 0; r < 16; ++r) otacc[dch][r] = 0.f;

    // prologue: stage units 0,1,2 into bufs 0,1,2
    STAGE(SRCU(0), 0);
    STAGE(SRCU(1), 1);
    STAGE(SRCU(2), 2);

    for (int u = 0; u < 33; ++u) {
        // counted wait: drain stage u only (issued 3 iterations ago);
        // stages u+1, u+2 (16 loads) stay in flight.
        asm volatile("s_waitcnt vmcnt(16)" ::: "memory");
        __builtin_amdgcn_s_barrier();
        {   // issue stage u+3 (dummy re-stage of unit 32 at the tail)
            const int sn = u + 3 <= 32 ? u + 3 : 32;
            STAGE(SRCU(sn), (u + 3) & 3);
        }

        unsigned short* Ks = smem + (u & 3) * 16384;
        unsigned short* Vs = Ks + 8192;

        const bool atD  = (u == qtA) || (u == 32);   // diagonal unit
        const bool dead = atD && (wj > wq2);
        if (!dead) {
            const int jrow = wj * 32 + qcol;

            // batch-issue operand reads (8 K-frags + 8 V-frags)
            bf16x8 kf[8], vf[8];
            #pragma unroll
            for (int ks = 0; ks < 8; ++ks) {
                const int c = ks * 2 + hi;
                kf[ks] = *(const bf16x8*)&Ks[(jrow * 16 + (c ^ (lane & 15))) * 8];
            }
            #pragma unroll
            for (int ks2 = 0; ks2 < 2; ++ks2)
                #pragma unroll
                for (int dch = 0; dch < 4; ++dch) {
                    const int c = wj * 4 + ks2 * 2 + hi;
                    const int drow = dch * 32 + qcol;
                    vf[ks2 * 4 + dch] = *(const bf16x8*)&Vs[(drow * 8 + (c ^ (lane & 7))) * 8];
                }

            // ---- S^T = K Q^T : two parallel accumulation chains ----
            f32x16 sacc0, sacc1;
            #pragma unroll
            for (int r = 0; r < 16; ++r) { sacc0[r] = 0.f; sacc1[r] = 0.f; }
            __builtin_amdgcn_s_setprio(1);
            #pragma unroll
            for (int ks = 0; ks < 8; ks += 2) {
                sacc0 = __builtin_amdgcn_mfma_f32_32x32x16_bf16(kf[ks], qf[ks], sacc0, 0, 0, 0);
                sacc1 = __builtin_amdgcn_mfma_f32_32x32x16_bf16(kf[ks + 1], qf[ks + 1], sacc1, 0, 0, 0);
            }
            __builtin_amdgcn_s_setprio(0);
            f32x16 sacc = sacc0 + sacc1;

            if (atD && wj == wq2) {              // diagonal 32x32 mask
                #pragma unroll
                for (int r = 0; r < 16; ++r) {
                    const int jl = (r & 3) + 8 * (r >> 2) + 4 * hi;
                    if (qcol < jl) sacc[r] = -1e30f;
                }
            }

            unsigned int dw[8];
            #pragma unroll
            for (int m2 = 0; m2 < 8; ++m2) {
                const float p0 = __expf(sacc[2 * m2]);
                const float p1 = __expf(sacc[2 * m2 + 1]);
                lsum += p0 + p1;
                dw[m2] = pk2bf(p0, p1);
            }

            // P^T C-layout -> PV B-frags via permlane32_swap
            __builtin_amdgcn_s_setprio(1);
            #pragma unroll
            for (int ks2 = 0; ks2 < 2; ++ks2) {
                const uint32x2 s02 = __builtin_amdgcn_permlane32_swap(
                    dw[4 * ks2 + 0], dw[4 * ks2 + 2], 0, 0);
                const uint32x2 s13 = __builtin_amdgcn_permlane32_swap(
                    dw[4 * ks2 + 1], dw[4 * ks2 + 3], 0, 0);
                union { unsigned int u2[4]; bf16x8 v; } pf;
                pf.u2[0] = s02[0];
                pf.u2[1] = s13[0];
                pf.u2[2] = s02[1];
                pf.u2[3] = s13[1];
                #pragma unroll
                for (int dch = 0; dch < 4; ++dch)
                    otacc[dch] = __builtin_amdgcn_mfma_f32_32x32x16_bf16(vf[ks2 * 4 + dch], pf.v, otacc[dch], 0, 0, 0);
            }
            __builtin_amdgcn_s_setprio(0);
        }

        if (u == qtA) {
            // ---- tile A epilogue: merge wj pairs via freed buf (u&3) ----
            float* scr = (float*)(smem + (u & 3) * 16384);   // [64][128] f32
            lsum += __shfl_xor(lsum, 32);
            __syncthreads();                 // all compute on buf u done
            const int row = wq2 * 32 + qcol;
            if (wj == 1) {
                float* s0 = scr + (size_t)row * 128;
                #pragma unroll
                for (int dch = 0; dch < 4; ++dch)
                    #pragma unroll
                    for (int r = 0; r < 16; ++r)
                        s0[dch * 32 + (r & 3) + 8 * (r >> 2) + 4 * hi] = otacc[dch][r];
                if (hi == 0) lscr[row] = lsum;
            }
            __syncthreads();
            if (wj == 0) {
                const float l = lsum + lscr[row];
                const float inv = 1.0f / l;
                const float* s0 = scr + (size_t)row * 128;
                unsigned short* op = o + bhbase + (size_t)(qtA * 64 + row) * 1024;
                #pragma unroll
                for (int dch = 0; dch < 4; ++dch)
                    #pragma unroll
                    for (int k4 = 0; k4 < 4; ++k4) {
                        const int d0 = dch * 32 + 8 * k4 + 4 * hi;
                        const float f0 = (otacc[dch][4 * k4 + 0] + s0[d0 + 0]) * inv;
                        const float f1 = (otacc[dch][4 * k4 + 1] + s0[d0 + 1]) * inv;
                        const float f2 = (otacc[dch][4 * k4 + 2] + s0[d0 + 2]) * inv;
                        const float f3 = (otacc[dch][4 * k4 + 3] + s0[d0 + 3]) * inv;
                        uint2 val;
                        val.x = pk2bf(f0, f1);
                        val.y = pk2bf(f2, f3);
                        *(uint2*)(op + d0) = val;
                    }
            }
            // reset accumulators, load Q frags for tile B
            lsum = 0.f;
            #pragma unroll
            for (int dch = 0; dch < 4; ++dch)
                #pragma unroll
                for (int r = 0; r < 16; ++r) otacc[dch][r] = 0.f;
            const unsigned short* qp = qb + bhbase
                + (size_t)(qtB * 64 + wq2 * 32 + qcol) * 1024 + hi * 8;
            #pragma unroll
            for (int ks = 0; ks < 8; ++ks)
                qf[ks] = *(const bf16x8*)(qp + ks * 16);
            // note: next loop top's barrier orders these scr reads/writes
            // before any STAGE overwrites buf (u&3) (first reuse is u+4).
        }
    }

    // ---- tile B epilogue (buf 32&3 = 0 freed; dummies went to 1,2,3) ----
    {
        float* scr = (float*)smem;                   // buf 0
        lsum += __shfl_xor(lsum, 32);
        __syncthreads();
        const int row = wq2 * 32 + qcol;
        if (wj == 1) {
            float* s0 = scr + (size_t)row * 128;
            #pragma unroll
            for (int dch = 0; dch < 4; ++dch)
                #pragma unroll
                for (int r = 0; r < 16; ++r)
                    s0[dch * 32 + (r & 3) + 8 * (r >> 2) + 4 * hi] = otacc[dch][r];
            if (hi == 0) lscr[row] = lsum;
        }
        __syncthreads();
        if (wj == 0) {
            const float l = lsum + lscr[row];
            const float inv = 1.0f / l;
            const float* s0 = scr + (size_t)row * 128;
            unsigned short* op = o + bhbase + (size_t)(qtB * 64 + row) * 1024;
            #pragma unroll
            for (int dch = 0; dch < 4; ++dch)
                #pragma unroll
                for (int k4 = 0; k4 < 4; ++k4) {
                    const int d0 = dch * 32 + 8 * k4 + 4 * hi;
                    const float f0 = (otacc[dch][4 * k4 + 0] + s0[d0 + 0]) * inv;
                    const float f1 = (otacc[dch][4 * k4 + 1] + s0[d0 + 1]) * inv;
                    const float f2 = (otacc[dch][4 * k4 + 2] + s0[d0 + 2]) * inv;
                    const float f3 = (otacc[dch][4 * k4 + 3] + s0[d0 + 3]) * inv;
                    uint2 val;
                    val.x = pk2bf(f0, f1);
                    val.y = pk2bf(f2, f3);
                    *(uint2*)(op + d0) = val;
                }
        }
    }
#undef STAGE
#undef SRCU
}

// ---------------------------------------------------------------------------
extern "C" void kernel_launch(void* const* d_in, const int* in_sizes, int n_in,
                              void* d_out, int out_size, void* d_ws, size_t ws_size,
                              hipStream_t stream)
{
    const float* x  = (const float*)d_in[0];
    const float* wq = (const float*)d_in[1];
    const float* wk = (const float*)d_in[2];
    const float* wv = (const float*)d_in[3];
    const float* wo = (const float*)d_in[4];
    float* out = (float*)d_out;

    const size_t SZ = (size_t)NROW * HD;               // 4M elements
    unsigned short* qb    = (unsigned short*)d_ws;     // 8 MB
    unsigned short* kb    = qb + SZ;                   // 8 MB
    unsigned short* vt    = kb + SZ;                   // 8 MB [(b,h),d,t]
    unsigned short* ob    = vt + SZ;                   // 8 MB
    unsigned short* xb    = ob + SZ;                   // 8 MB
    unsigned short* wqkvT = xb + SZ;                   // 6 MB [3072][1024]
    unsigned short* woT   = wqkvT + 3 * 1024 * 1024;   // 2 MB

    // prologue: x cast + 4 weight transposes, one launch
    prep<<<dim3(32, 32, 5), 256, 0, stream>>>(x, wq, wk, wv, wo, xb, wqkvT, woT);

    // fused QKV projection (+ RMSNorm/RoPE on q,k; V written transposed)
    gemm_qkv<<<dim3(24, 32), 256, 0, stream>>>(xb, wqkvT, qb, kb, vt);

    // paired, deep-pipelined flash attention: 256 blocks (16 bh x 16 pairs)
    flash_attn<<<dim3(256), 256, 0, stream>>>(qb, kb, vt, ob);

    // output projection, 128x64 tiles -> 512 blocks
    gemm_out<<<dim3(16, 32), 256, 0, stream>>>(ob, woT, out);
}

// Round 8
// 187.659 us; speedup vs baseline: 1.0177x; 1.0177x over previous
//
#include <hip/hip_runtime.h>
#include <hip/hip_bf16.h>
#include <math.h>

// Problem constants: B=2, T=2048, M=1024, H=8, D=128
#define B_  2
#define T_  2048
#define M_  1024
#define H_  8
#define D_  128
#define NROW (B_ * T_)          // 4096
#define HD  (H_ * D_)           // 1024

#define NORM_EPS 1e-6f
#define QK_MULT  0.08838834764831845f   // sqrt(1/128)
#define LN_BASE_64 0.14391156510f       // ln(10000)/64

typedef short bf16x8  __attribute__((ext_vector_type(8)));    // 8 bf16 = 4 VGPRs
typedef float f32x4   __attribute__((ext_vector_type(4)));
typedef float f32x16  __attribute__((ext_vector_type(16)));
typedef unsigned int uint32x2 __attribute__((ext_vector_type(2)));

static __device__ __forceinline__ unsigned short f2bf(float f) {
    union { __hip_bfloat16 h; unsigned short u; } cv;
    cv.h = __float2bfloat16(f);
    return cv.u;
}
static __device__ __forceinline__ unsigned int pk2bf(float a, float b) {
    return ((unsigned int)f2bf(b) << 16) | f2bf(a);
}

// async global->LDS, 16 bytes per lane. LDS dest = wave-uniform base + lane*16.
static __device__ __forceinline__ void gload_lds16(const unsigned short* g,
                                                   unsigned short* l) {
    __builtin_amdgcn_global_load_lds(
        (const __attribute__((address_space(1))) void*)g,
        (__attribute__((address_space(3))) void*)l, 16, 0, 0);
}

// ---------------------------------------------------------------------------
// prep: z<4 -> transpose+cast weight z (out[n][k]=bf16(in[k][n]));
//       z==4 -> linear cast of x to bf16.
// ---------------------------------------------------------------------------
__global__ __launch_bounds__(256) void prep(const float* __restrict__ x,
                                            const float* __restrict__ w0,
                                            const float* __restrict__ w1,
                                            const float* __restrict__ w2,
                                            const float* __restrict__ w3,
                                            unsigned short* __restrict__ xb,
                                            unsigned short* __restrict__ wqkvT,
                                            unsigned short* __restrict__ woT)
{
    __shared__ float t[32][33];
    const int z = blockIdx.z;
    if (z == 4) {
        const size_t base = ((size_t)blockIdx.y * 32 + blockIdx.x) * 4096;
        #pragma unroll
        for (int it = 0; it < 4; ++it) {
            const size_t i = base + it * 1024 + threadIdx.x * 4;
            const float4 v = *(const float4*)(x + i);
            ushort4 o;
            o.x = f2bf(v.x); o.y = f2bf(v.y); o.z = f2bf(v.z); o.w = f2bf(v.w);
            *(ushort4*)(xb + i) = o;
        }
        return;
    }
    const float* in = z == 0 ? w0 : (z == 1 ? w1 : (z == 2 ? w2 : w3));
    unsigned short* out = z < 3 ? (wqkvT + (size_t)z * 1024 * 1024) : woT;

    const int tx = threadIdx.x & 31;
    const int ty = threadIdx.x >> 5;
    const int n0 = blockIdx.x * 32;
    const int k0 = blockIdx.y * 32;
    #pragma unroll
    for (int r = 0; r < 4; ++r)
        t[ty + r * 8][tx] = in[(size_t)(k0 + ty + r * 8) * 1024 + n0 + tx];
    __syncthreads();
    #pragma unroll
    for (int r = 0; r < 4; ++r)
        out[(size_t)(n0 + ty + r * 8) * 1024 + k0 + tx] = f2bf(t[tx][ty + r * 8]);
}

// ---------------------------------------------------------------------------
// QKV GEMM: C = A[4096x1024] * Bt[3072x1024]^T. 128x128 tile, BK=32,
// async double-buffered global_load_lds staging, 3 blocks/CU. V epilogue
// transposes via LDS so vt is written in contiguous 256-B rows.
// ---------------------------------------------------------------------------
__global__ __launch_bounds__(256) void gemm_qkv(const unsigned short* __restrict__ A,
                                                const unsigned short* __restrict__ Bt,
                                                unsigned short* __restrict__ oq,
                                                unsigned short* __restrict__ ok,
                                                unsigned short* __restrict__ vt)
{
    __shared__ __align__(16) unsigned short smem[17408];   // 34 KB
    #define AsQ(buf) (smem + (buf) * 4096)
    #define BsQ(buf) (smem + 8192 + (buf) * 4096)

    const int tid  = threadIdx.x;
    const int lane = tid & 63;
    const int w    = tid >> 6;          // wave = row band (32 rows)
    const int g    = lane >> 4;
    const int lc   = lane & 15;

    const int m0 = blockIdx.y * 128;
    const int n0 = blockIdx.x * 128;

    const unsigned short* aBase = A  + (size_t)m0 * 1024;
    const unsigned short* bBase = Bt + (size_t)n0 * 1024;

    int dstOff[2];
    size_t srcOff[2];
    #pragma unroll
    for (int it = 0; it < 2; ++it) {
        const int u  = tid + it * 256;      // 0..511
        const int r2 = u >> 2;              // tile row
        const int sg = (u & 3) ^ (r2 & 3);  // src segment (XOR swizzle)
        dstOff[it] = u * 8;
        srcOff[it] = (size_t)r2 * 1024 + sg * 8;
    }

    f32x4 acc[2][8];
    #pragma unroll
    for (int i = 0; i < 2; ++i)
        #pragma unroll
        for (int j = 0; j < 8; ++j)
            acc[i][j] = (f32x4){0.f, 0.f, 0.f, 0.f};

    #pragma unroll
    for (int it = 0; it < 2; ++it) {
        gload_lds16(aBase + srcOff[it], AsQ(0) + dstOff[it]);
        gload_lds16(bBase + srcOff[it], BsQ(0) + dstOff[it]);
    }

    for (int kt = 0; kt < 32; ++kt) {
        const int cur = kt & 1;
        __syncthreads();                      // tile kt ready; buf^1 free

        if (kt < 31) {                        // async-prefetch next K-tile
            const int k0n = (kt + 1) * 32;
            #pragma unroll
            for (int it = 0; it < 2; ++it) {
                gload_lds16(aBase + srcOff[it] + k0n, AsQ(cur ^ 1) + dstOff[it]);
                gload_lds16(bBase + srcOff[it] + k0n, BsQ(cur ^ 1) + dstOff[it]);
            }
        }

        const int sw = (g ^ (lc & 3)) << 3;
        bf16x8 af[2], bfr[8];
        #pragma unroll
        for (int i = 0; i < 2; ++i)
            af[i] = *(const bf16x8*)&AsQ(cur)[(w * 32 + i * 16 + lc) * 32 + sw];
        #pragma unroll
        for (int j = 0; j < 8; ++j)
            bfr[j] = *(const bf16x8*)&BsQ(cur)[(j * 16 + lc) * 32 + sw];

        #pragma unroll
        for (int i = 0; i < 2; ++i)
            #pragma unroll
            for (int j = 0; j < 8; ++j)
                acc[i][j] = __builtin_amdgcn_mfma_f32_16x16x32_bf16(af[i], bfr[j], acc[i][j], 0, 0, 0);
    }

    const int which = n0 >> 10;
    const int ncol0 = n0 & 1023;            // head-aligned (tile = one head)
    if (which < 2) {
        // ---- fused RMSNorm + RoPE + sqrt(qk_scale) for q / k ----
        unsigned short* outp = which == 0 ? oq : ok;
        float freq[4];
        #pragma unroll
        for (int j = 0; j < 4; ++j)
            freq[j] = __expf(-(float)(j * 16 + lc) * LN_BASE_64);

        #pragma unroll
        for (int i = 0; i < 2; ++i)
            #pragma unroll
            for (int r = 0; r < 4; ++r) {
                float s = 0.f;
                #pragma unroll
                for (int j = 0; j < 8; ++j) s += acc[i][j][r] * acc[i][j][r];
                #pragma unroll
                for (int off = 1; off < 16; off <<= 1) s += __shfl_xor(s, off);
                const float rms = rsqrtf(s * (1.0f / 128.0f) + NORM_EPS) * QK_MULT;

                const int trow = m0 + w * 32 + i * 16 + g * 4 + r;
                const float tpos = (float)(trow & (T_ - 1));
                unsigned short* op = outp + (size_t)trow * 1024 + ncol0;
                #pragma unroll
                for (int j = 0; j < 4; ++j) {
                    float sn, cs;
                    __sincosf(tpos * freq[j], &sn, &cs);
                    const float e = acc[i][j][r] * rms;       // even half
                    const float o = acc[i][j + 4][r] * rms;   // odd half (+64)
                    op[j * 16 + lc]      = f2bf(e * cs - o * sn);
                    op[j * 16 + lc + 64] = f2bf(e * sn + o * cs);
                }
            }
    } else {
        // V: transpose in LDS, then dump contiguous 256-B rows ->
        // vt[(b*8+h)*128 + d][t]. Full-line writes, no write-allocate RMW.
        const int b2 = m0 >> 11;
        const int hh = ncol0 >> 7;
        const int PAD = 136;                 // 272 B rows: 16-B aligned, odd*16
        __syncthreads();                     // staging reads done; reuse smem
        #pragma unroll
        for (int i = 0; i < 2; ++i) {
            const int t0 = w * 32 + i * 16 + g * 4;
            #pragma unroll
            for (int j = 0; j < 8; ++j) {
                uint2 val;
                val.x = pk2bf(acc[i][j][0], acc[i][j][1]);
                val.y = pk2bf(acc[i][j][2], acc[i][j][3]);
                *(uint2*)&smem[(j * 16 + lc) * PAD + t0] = val;
            }
        }
        __syncthreads();
        const int row  = tid >> 1;           // d (0..127)
        const int half = tid & 1;            // t half (64 shorts)
        const unsigned short* src = &smem[row * PAD + half * 64];
        unsigned short* dst = vt + ((size_t)(b2 * 8 + hh) * 128 + row) * T_
                                 + (m0 & 2047) + half * 64;
        #pragma unroll
        for (int it2 = 0; it2 < 8; ++it2)
            *(uint4*)(dst + it2 * 8) = *(const uint4*)(src + it2 * 8);
    }
    #undef AsQ
    #undef BsQ
}

// ---------------------------------------------------------------------------
// Output projection: C[4096x1024] fp32 = A * Bt^T. 128x64 tile (512 blocks,
// 3/CU, all resident), BK=64, async double-buffered staging + XOR swizzle.
// 2x2 waves of 64x32.
// ---------------------------------------------------------------------------
__global__ __launch_bounds__(256) void gemm_out(const unsigned short* __restrict__ A,
                                                const unsigned short* __restrict__ Bt,
                                                float* __restrict__ cf)
{
    __shared__ unsigned short As[2][128 * 64];   // 2 x 16 KB
    __shared__ unsigned short Bs[2][64 * 64];    // 2 x 8 KB  (48 KB total)

    const int tid  = threadIdx.x;
    const int lane = tid & 63;
    const int w    = tid >> 6;
    const int g    = lane >> 4;
    const int lc   = lane & 15;
    const int wm   = w >> 1;
    const int wn   = w & 1;

    const int m0 = blockIdx.y * 128;
    const int n0 = blockIdx.x * 64;

    const unsigned short* aBase = A  + (size_t)m0 * 1024;
    const unsigned short* bBase = Bt + (size_t)n0 * 1024;

    int dstA[4], dstB[2];
    size_t srcA[4], srcB[2];
    #pragma unroll
    for (int it = 0; it < 4; ++it) {
        const int u  = tid + it * 256;
        const int r2 = u >> 3;
        const int sg = (u & 7) ^ (r2 & 7);
        dstA[it] = u * 8;
        srcA[it] = (size_t)r2 * 1024 + sg * 8;
    }
    #pragma unroll
    for (int it = 0; it < 2; ++it) {
        const int u  = tid + it * 256;
        const int r2 = u >> 3;
        const int sg = (u & 7) ^ (r2 & 7);
        dstB[it] = u * 8;
        srcB[it] = (size_t)r2 * 1024 + sg * 8;
    }

    f32x4 acc[4][2];
    #pragma unroll
    for (int i = 0; i < 4; ++i)
        #pragma unroll
        for (int j = 0; j < 2; ++j)
            acc[i][j] = (f32x4){0.f, 0.f, 0.f, 0.f};

    #pragma unroll
    for (int it = 0; it < 4; ++it)
        gload_lds16(aBase + srcA[it], &As[0][dstA[it]]);
    #pragma unroll
    for (int it = 0; it < 2; ++it)
        gload_lds16(bBase + srcB[it], &Bs[0][dstB[it]]);

    for (int kt = 0; kt < 16; ++kt) {
        const int cur = kt & 1;
        __syncthreads();

        if (kt < 15) {
            const int k0n = (kt + 1) * 64;
            #pragma unroll
            for (int it = 0; it < 4; ++it)
                gload_lds16(aBase + srcA[it] + k0n, &As[cur ^ 1][dstA[it]]);
            #pragma unroll
            for (int it = 0; it < 2; ++it)
                gload_lds16(bBase + srcB[it] + k0n, &Bs[cur ^ 1][dstB[it]]);
        }

        #pragma unroll
        for (int dc = 0; dc < 2; ++dc) {
            const int sw = ((dc * 4 + g) ^ (lc & 7)) << 3;
            bf16x8 af[4], bfr[2];
            #pragma unroll
            for (int i = 0; i < 4; ++i)
                af[i] = *(const bf16x8*)&As[cur][(wm * 64 + i * 16 + lc) * 64 + sw];
            #pragma unroll
            for (int j = 0; j < 2; ++j)
                bfr[j] = *(const bf16x8*)&Bs[cur][(wn * 32 + j * 16 + lc) * 64 + sw];

            #pragma unroll
            for (int i = 0; i < 4; ++i)
                #pragma unroll
                for (int j = 0; j < 2; ++j)
                    acc[i][j] = __builtin_amdgcn_mfma_f32_16x16x32_bf16(af[i], bfr[j], acc[i][j], 0, 0, 0);
        }
    }

    #pragma unroll
    for (int i = 0; i < 4; ++i) {
        const int mrow = m0 + wm * 64 + i * 16 + g * 4;
        #pragma unroll
        for (int j = 0; j < 2; ++j) {
            const int nc = n0 + wn * 32 + j * 16 + lc;
            #pragma unroll
            for (int r = 0; r < 4; ++r)
                cf[(size_t)(mrow + r) * 1024 + nc] = acc[i][j][r];
        }
    }
}

// ---------------------------------------------------------------------------
// Flash attention v8: DUAL-GROUP fused block -> 2 waves/SIMD.
// R7 diagnosis: 33 uniform iters/CU but 4218 cy/iter with 1 wave/SIMD --
// half the iteration is unhidden serial latency (ds_read chains, MFMA
// chains, vmcnt). Fix: the 33-unit pair stream (tile qtA then tile
// qtB=31-qtA; R7-proven) is SPLIT AT UNIT 17 across two 4-wave groups of
// ONE 512-thread block: group0 = positions 0..16 (all of tile A since
// qtA<=15, plus a tile-B prefix), group1 = positions 17..32 (pure tile B,
// +1 dead slot). 17 lockstep iterations for every block; tile-B partials
// merge through LDS at the end (in-block = legal). 2 waves/SIMD: while one
// wave waits on lgkm/MFMA, its SIMD-mate from the other group issues.
// Each group: private 2x32 KB double buffer (128 KB total, 1 block/CU),
// stage-at-end + counted vmcnt(8) (1-iter DMA lead). Same-CU XCD mapping
// as R7 (bid&7 -> 2 bh/XCD, L2-resident K/V).
// Bank-conflict fixes: A-epilogue scratch rotated (d+row)&127 (scalar,
// conflict-free); B-epilogue slabs stride-129 in the fully-freed 128 KB.
// ---------------------------------------------------------------------------
__global__ __launch_bounds__(512) void flash_attn(const unsigned short* __restrict__ qb,
                                                  const unsigned short* __restrict__ kb,
                                                  const unsigned short* __restrict__ vt,
                                                  unsigned short* __restrict__ o)
{
    // 2 groups x 2 bufs x (K 16KB | V 16KB) = 128 KB + 1 KB lscr
    __shared__ __align__(16) unsigned short smem[65536 + 512];
    float* lscrA = (float*)(smem + 65536);        // [64]
    float* lscrB = lscrA + 64;                    // [3][64]

    const int tid  = threadIdx.x;
    const int lane = tid & 63;
    const int w    = tid >> 6;          // 0..7
    const int g2   = w >> 2;            // stream group
    const int wj   = (w >> 1) & 1;      // j-half within group
    const int wq2  = w & 1;             // q-half
    const int qcol = lane & 31;
    const int hi   = lane >> 5;         // half-wave
    const int gtid = tid & 255;         // thread id within group

    // XCD-aware unit mapping: 256 blocks = 16 bh x 16 pairs
    const int bid = blockIdx.x;
    const int s   = bid >> 3;
    const int bh  = (bid & 7) + 8 * (s & 1);
    const int qtA = s >> 1;             // 0..15
    const int qtB = 31 - qtA;           // 16..31
    const int h   = bh & (H_ - 1);
    const int b   = bh >> 3;

    const size_t bhbase  = (size_t)b * T_ * HD + (size_t)h * 128;   // q,k,o
    const size_t bhvbase = (size_t)bh * 128 * T_;                   // vt

    int mI[4];
    size_t srcKoff[4], srcVoff[4];
    #pragma unroll
    for (int it = 0; it < 4; ++it) {
        const int m = (((gtid >> 6) * 4 + it)) * 64 + (gtid & 63);   // 0..1023
        mI[it] = m;
        const int jK = m >> 4, cK = (m & 15) ^ (jK & 15);
        srcKoff[it] = (size_t)jK * 1024 + cK * 8;
        const int dV = m >> 3, cV = (m & 7) ^ (dV & 7);
        srcVoff[it] = (size_t)dV * T_ + cV * 8;
    }
    const unsigned short* kgb = kb + bhbase;
    const unsigned short* vgb = vt + bhvbase;
    unsigned short* gbase = smem + g2 * 32768;    // group's 2-buffer region

    // stream position p -> KV unit (tile A: 0..qtA, then tile B: 0..qtB)
#define SRCU(p_) ((p_) > qtA ? (p_) - qtA - 1 : (p_))
#define STAGE(p_, l_) {                                                      \
        const size_t jo = (size_t)SRCU(p_) * 64;                             \
        unsigned short* Kd = gbase + ((l_) & 1) * 16384;                     \
        unsigned short* Vd = Kd + 8192;                                      \
        _Pragma("unroll")                                                    \
        for (int it = 0; it < 4; ++it)                                       \
            gload_lds16(kgb + jo * 1024 + srcKoff[it], &Kd[mI[it] * 8]);     \
        _Pragma("unroll")                                                    \
        for (int it = 0; it < 4; ++it)                                       \
            gload_lds16(vgb + jo + srcVoff[it], &Vd[mI[it] * 8]);            \
    }

    // Q frags: group0 starts on tile A, group1 on tile B
    bf16x8 qf[8];
    {
        const int qt0 = g2 ? qtB : qtA;
        const unsigned short* qp = qb + bhbase
            + (size_t)(qt0 * 64 + wq2 * 32 + qcol) * 1024 + hi * 8;
        #pragma unroll
        for (int ks = 0; ks < 8; ++ks)
            qf[ks] = *(const bf16x8*)(qp + ks * 16);
    }

    float lsum = 0.f;
    f32x16 otacc[4];
    #pragma unroll
    for (int dch = 0; dch < 4; ++dch)
        #pragma unroll
        for (int r = 0; r < 16; ++r) otacc[dch][r] = 0.f;

    // prologue: each group stages its local positions 0,1
    STAGE(g2 * 17 + 0, 0);
    STAGE(g2 ? 18 : 1, 1);

    for (int u = 0; u < 17; ++u) {
        // counted wait: drain own-group stage u (issued 1 iter ago);
        // stage u+1 (8 loads) stays in flight.
        if (u < 16) asm volatile("s_waitcnt vmcnt(8)" ::: "memory");
        else        asm volatile("s_waitcnt vmcnt(0)" ::: "memory");
        __builtin_amdgcn_s_barrier();           // all quarters of buf landed

        const int p = u + g2 * 17;              // stream position
        const bool livep = (p <= 32);
        const bool atD = (p == qtA) || (p == 32);
        if (livep && !(atD && (wj > wq2))) {
            unsigned short* Ks = gbase + (u & 1) * 16384;
            unsigned short* Vs = Ks + 8192;
            const int jrow = wj * 32 + qcol;

            // batch-issue operand reads (8 K-frags + 8 V-frags)
            bf16x8 kf[8], vf[8];
            #pragma unroll
            for (int ks = 0; ks < 8; ++ks) {
                const int c = ks * 2 + hi;
                kf[ks] = *(const bf16x8*)&Ks[(jrow * 16 + (c ^ (lane & 15))) * 8];
            }
            #pragma unroll
            for (int ks2 = 0; ks2 < 2; ++ks2)
                #pragma unroll
                for (int dch = 0; dch < 4; ++dch) {
                    const int c = wj * 4 + ks2 * 2 + hi;
                    const int drow = dch * 32 + qcol;
                    vf[ks2 * 4 + dch] = *(const bf16x8*)&Vs[(drow * 8 + (c ^ (lane & 7))) * 8];
                }

            // ---- S^T = K Q^T : two parallel accumulation chains ----
            f32x16 sacc0, sacc1;
            #pragma unroll
            for (int r = 0; r < 16; ++r) { sacc0[r] = 0.f; sacc1[r] = 0.f; }
            __builtin_amdgcn_s_setprio(1);
            #pragma unroll
            for (int ks = 0; ks < 8; ks += 2) {
                sacc0 = __builtin_amdgcn_mfma_f32_32x32x16_bf16(kf[ks], qf[ks], sacc0, 0, 0, 0);
                sacc1 = __builtin_amdgcn_mfma_f32_32x32x16_bf16(kf[ks + 1], qf[ks + 1], sacc1, 0, 0, 0);
            }
            __builtin_amdgcn_s_setprio(0);
            f32x16 sacc = sacc0 + sacc1;

            if (atD && wj == wq2) {              // diagonal 32x32 mask
                #pragma unroll
                for (int r = 0; r < 16; ++r) {
                    const int jl = (r & 3) + 8 * (r >> 2) + 4 * hi;
                    if (qcol < jl) sacc[r] = -1e30f;
                }
            }

            unsigned int dw[8];
            #pragma unroll
            for (int m2 = 0; m2 < 8; ++m2) {
                const float p0 = __expf(sacc[2 * m2]);
                const float p1 = __expf(sacc[2 * m2 + 1]);
                lsum += p0 + p1;
                dw[m2] = pk2bf(p0, p1);
            }

            // P^T C-layout -> PV B-frags via permlane32_swap
            __builtin_amdgcn_s_setprio(1);
            #pragma unroll
            for (int ks2 = 0; ks2 < 2; ++ks2) {
                const uint32x2 s02 = __builtin_amdgcn_permlane32_swap(
                    dw[4 * ks2 + 0], dw[4 * ks2 + 2], 0, 0);
                const uint32x2 s13 = __builtin_amdgcn_permlane32_swap(
                    dw[4 * ks2 + 1], dw[4 * ks2 + 3], 0, 0);
                union { unsigned int u2[4]; bf16x8 v; } pf;
                pf.u2[0] = s02[0];
                pf.u2[1] = s13[0];
                pf.u2[2] = s02[1];
                pf.u2[3] = s13[1];
                #pragma unroll
                for (int dch = 0; dch < 4; ++dch)
                    otacc[dch] = __builtin_amdgcn_mfma_f32_32x32x16_bf16(vf[ks2 * 4 + dch], pf.v, otacc[dch], 0, 0, 0);
            }
            __builtin_amdgcn_s_setprio(0);
        }

        if (u == qtA) {
            // ---- tile A epilogue (group0-internal; block-uniform u so all
            // 8 waves pass the barriers). Scratch = group0's freed buffer.
            float* scrA = (float*)(smem + (qtA & 1) * 16384);   // 32 KB
            float lsA = 0.f;
            if (g2 == 0) { lsA = lsum + __shfl_xor(lsum, 32); }
            asm volatile("s_waitcnt lgkmcnt(0)" ::: "memory");
            __builtin_amdgcn_s_barrier();
            const int row = wq2 * 32 + qcol;
            if (g2 == 0 && wj == 1) {
                float* s0 = scrA + (size_t)row * 128;
                #pragma unroll
                for (int dch = 0; dch < 4; ++dch)
                    #pragma unroll
                    for (int r = 0; r < 16; ++r) {
                        const int d = dch * 32 + (r & 3) + 8 * (r >> 2) + 4 * hi;
                        s0[(d + row) & 127] = otacc[dch][r];   // rotation: conflict-free
                    }
                if (hi == 0) lscrA[row] = lsA;
            }
            asm volatile("s_waitcnt lgkmcnt(0)" ::: "memory");
            __builtin_amdgcn_s_barrier();
            if (g2 == 0) {
                if (wj == 0) {
                    const float l = lsA + lscrA[row];
                    const float inv = 1.0f / l;
                    const float* s0 = scrA + (size_t)row * 128;
                    unsigned short* op = o + bhbase + (size_t)(qtA * 64 + row) * 1024;
                    #pragma unroll
                    for (int dch = 0; dch < 4; ++dch)
                        #pragma unroll
                        for (int k4 = 0; k4 < 4; ++k4) {
                            const int d0 = dch * 32 + 8 * k4 + 4 * hi;
                            const float f0 = (otacc[dch][4 * k4 + 0] + s0[(d0 + 0 + row) & 127]) * inv;
                            const float f1 = (otacc[dch][4 * k4 + 1] + s0[(d0 + 1 + row) & 127]) * inv;
                            const float f2 = (otacc[dch][4 * k4 + 2] + s0[(d0 + 2 + row) & 127]) * inv;
                            const float f3 = (otacc[dch][4 * k4 + 3] + s0[(d0 + 3 + row) & 127]) * inv;
                            uint2 val;
                            val.x = pk2bf(f0, f1);
                            val.y = pk2bf(f2, f3);
                            *(uint2*)(op + d0) = val;
                        }
                }
                // reset accumulators; switch to tile B
                lsum = 0.f;
                #pragma unroll
                for (int dch = 0; dch < 4; ++dch)
                    #pragma unroll
                    for (int r = 0; r < 16; ++r) otacc[dch][r] = 0.f;
                const unsigned short* qp = qb + bhbase
                    + (size_t)(qtB * 64 + wq2 * 32 + qcol) * 1024 + hi * 8;
                #pragma unroll
                for (int ks = 0; ks < 8; ++ks)
                    qf[ks] = *(const bf16x8*)(qp + ks * 16);
            }
        }

        __builtin_amdgcn_s_barrier();       // all reads of buf (u&1) done
        const int ln = u + 2;
        if (ln <= 16) {
            // group1 position capped at 32: ln==16 stages a harmless dummy
            // (re-stage of pos 32) into a buffer that is never read again.
            const int pp = g2 ? (ln + 17 > 32 ? 32 : ln + 17) : ln;
            STAGE(pp, ln);
        }
    }

    // ---- tile B epilogue: merge 4 partials (2 groups x 2 wj) via LDS ----
    {
        lsum += __shfl_xor(lsum, 32);
        asm volatile("s_waitcnt lgkmcnt(0)" ::: "memory");
        __builtin_amdgcn_s_barrier();
        const int row  = wq2 * 32 + qcol;
        const int slab = g2 * 2 + wj;               // 0..3; 0 = reader
        float* scrB = (float*)smem;                 // [3][64][129] f32 = 99 KB
        if (slab > 0) {
            float* s0 = scrB + (size_t)(slab - 1) * (64 * 129) + (size_t)row * 129;
            #pragma unroll
            for (int dch = 0; dch < 4; ++dch)
                #pragma unroll
                for (int r = 0; r < 16; ++r)
                    s0[dch * 32 + (r & 3) + 8 * (r >> 2) + 4 * hi] = otacc[dch][r];
            if (hi == 0) lscrB[(slab - 1) * 64 + row] = lsum;
        }
        asm volatile("s_waitcnt lgkmcnt(0)" ::: "memory");
        __builtin_amdgcn_s_barrier();
        if (slab == 0) {
            const float l = lsum + lscrB[row] + lscrB[64 + row] + lscrB[128 + row];
            const float inv = 1.0f / l;
            const float* s1 = scrB + (size_t)row * 129;
            const float* s2 = s1 + 64 * 129;
            const float* s3 = s2 + 64 * 129;
            unsigned short* op = o + bhbase + (size_t)(qtB * 64 + row) * 1024;
            #pragma unroll
            for (int dch = 0; dch < 4; ++dch)
                #pragma unroll
                for (int k4 = 0; k4 < 4; ++k4) {
                    const int d0 = dch * 32 + 8 * k4 + 4 * hi;
                    float f[4];
                    #pragma unroll
                    for (int i = 0; i < 4; ++i)
                        f[i] = (otacc[dch][4 * k4 + i] + s1[d0 + i] + s2[d0 + i] + s3[d0 + i]) * inv;
                    uint2 val;
                    val.x = pk2bf(f[0], f[1]);
                    val.y = pk2bf(f[2], f[3]);
                    *(uint2*)(op + d0) = val;
                }
        }
    }
#undef STAGE
#undef SRCU
}

// ---------------------------------------------------------------------------
extern "C" void kernel_launch(void* const* d_in, const int* in_sizes, int n_in,
                              void* d_out, int out_size, void* d_ws, size_t ws_size,
                              hipStream_t stream)
{
    const float* x  = (const float*)d_in[0];
    const float* wq = (const float*)d_in[1];
    const float* wk = (const float*)d_in[2];
    const float* wv = (const float*)d_in[3];
    const float* wo = (const float*)d_in[4];
    float* out = (float*)d_out;

    const size_t SZ = (size_t)NROW * HD;               // 4M elements
    unsigned short* qb    = (unsigned short*)d_ws;     // 8 MB
    unsigned short* kb    = qb + SZ;                   // 8 MB
    unsigned short* vt    = kb + SZ;                   // 8 MB [(b,h),d,t]
    unsigned short* ob    = vt + SZ;                   // 8 MB
    unsigned short* xb    = ob + SZ;                   // 8 MB
    unsigned short* wqkvT = xb + SZ;                   // 6 MB [3072][1024]
    unsigned short* woT   = wqkvT + 3 * 1024 * 1024;   // 2 MB

    // prologue: x cast + 4 weight transposes, one launch
    prep<<<dim3(32, 32, 5), 256, 0, stream>>>(x, wq, wk, wv, wo, xb, wqkvT, woT);

    // fused QKV projection (+ RMSNorm/RoPE on q,k; V written transposed)
    gemm_qkv<<<dim3(24, 32), 256, 0, stream>>>(xb, wqkvT, qb, kb, vt);

    // dual-group paired flash attention: 256 blocks x 512 thr, 17 iters each
    flash_attn<<<dim3(256), 512, 0, stream>>>(qb, kb, vt, ob);

    // output projection, 128x64 tiles -> 512 blocks
    gemm_out<<<dim3(16, 32), 256, 0, stream>>>(ob, woT, out);
}

// Round 9
// 185.316 us; speedup vs baseline: 1.0305x; 1.0126x over previous
//
#include <hip/hip_runtime.h>
#include <hip/hip_bf16.h>
#include <math.h>

// Problem constants: B=2, T=2048, M=1024, H=8, D=128
#define B_  2
#define T_  2048
#define M_  1024
#define H_  8
#define D_  128
#define NROW (B_ * T_)          // 4096
#define HD  (H_ * D_)           // 1024

#define NORM_EPS 1e-6f
#define QK_MULT  0.08838834764831845f   // sqrt(1/128)
#define LN_BASE_64 0.14391156510f       // ln(10000)/64

typedef short bf16x8  __attribute__((ext_vector_type(8)));    // 8 bf16 = 4 VGPRs
typedef float f32x4   __attribute__((ext_vector_type(4)));
typedef float f32x16  __attribute__((ext_vector_type(16)));
typedef unsigned int uint32x2 __attribute__((ext_vector_type(2)));

static __device__ __forceinline__ unsigned short f2bf(float f) {
    union { __hip_bfloat16 h; unsigned short u; } cv;
    cv.h = __float2bfloat16(f);
    return cv.u;
}
static __device__ __forceinline__ unsigned int pk2bf(float a, float b) {
    return ((unsigned int)f2bf(b) << 16) | f2bf(a);
}

// async global->LDS, 16 bytes per lane. LDS dest = wave-uniform base + lane*16.
static __device__ __forceinline__ void gload_lds16(const unsigned short* g,
                                                   unsigned short* l) {
    __builtin_amdgcn_global_load_lds(
        (const __attribute__((address_space(1))) void*)g,
        (__attribute__((address_space(3))) void*)l, 16, 0, 0);
}

// ---------------------------------------------------------------------------
// prep: z<4 -> transpose+cast weight z (out[n][k]=bf16(in[k][n]));
//       z==4 -> linear cast of x to bf16.
// ---------------------------------------------------------------------------
__global__ __launch_bounds__(256) void prep(const float* __restrict__ x,
                                            const float* __restrict__ w0,
                                            const float* __restrict__ w1,
                                            const float* __restrict__ w2,
                                            const float* __restrict__ w3,
                                            unsigned short* __restrict__ xb,
                                            unsigned short* __restrict__ wqkvT,
                                            unsigned short* __restrict__ woT)
{
    __shared__ float t[32][33];
    const int z = blockIdx.z;
    if (z == 4) {
        const size_t base = ((size_t)blockIdx.y * 32 + blockIdx.x) * 4096;
        #pragma unroll
        for (int it = 0; it < 4; ++it) {
            const size_t i = base + it * 1024 + threadIdx.x * 4;
            const float4 v = *(const float4*)(x + i);
            ushort4 o;
            o.x = f2bf(v.x); o.y = f2bf(v.y); o.z = f2bf(v.z); o.w = f2bf(v.w);
            *(ushort4*)(xb + i) = o;
        }
        return;
    }
    const float* in = z == 0 ? w0 : (z == 1 ? w1 : (z == 2 ? w2 : w3));
    unsigned short* out = z < 3 ? (wqkvT + (size_t)z * 1024 * 1024) : woT;

    const int tx = threadIdx.x & 31;
    const int ty = threadIdx.x >> 5;
    const int n0 = blockIdx.x * 32;
    const int k0 = blockIdx.y * 32;
    #pragma unroll
    for (int r = 0; r < 4; ++r)
        t[ty + r * 8][tx] = in[(size_t)(k0 + ty + r * 8) * 1024 + n0 + tx];
    __syncthreads();
    #pragma unroll
    for (int r = 0; r < 4; ++r)
        out[(size_t)(n0 + ty + r * 8) * 1024 + k0 + tx] = f2bf(t[tx][ty + r * 8]);
}

// ---------------------------------------------------------------------------
// QKV GEMM: C = A[4096x1024] * Bt[3072x1024]^T. 128x128 tile, BK=32,
// async double-buffered global_load_lds staging, 3 blocks/CU. V epilogue
// transposes via LDS so vt is written in contiguous 256-B rows.
// ---------------------------------------------------------------------------
__global__ __launch_bounds__(256) void gemm_qkv(const unsigned short* __restrict__ A,
                                                const unsigned short* __restrict__ Bt,
                                                unsigned short* __restrict__ oq,
                                                unsigned short* __restrict__ ok,
                                                unsigned short* __restrict__ vt)
{
    __shared__ __align__(16) unsigned short smem[17408];   // 34 KB
    #define AsQ(buf) (smem + (buf) * 4096)
    #define BsQ(buf) (smem + 8192 + (buf) * 4096)

    const int tid  = threadIdx.x;
    const int lane = tid & 63;
    const int w    = tid >> 6;          // wave = row band (32 rows)
    const int g    = lane >> 4;
    const int lc   = lane & 15;

    const int m0 = blockIdx.y * 128;
    const int n0 = blockIdx.x * 128;

    const unsigned short* aBase = A  + (size_t)m0 * 1024;
    const unsigned short* bBase = Bt + (size_t)n0 * 1024;

    int dstOff[2];
    size_t srcOff[2];
    #pragma unroll
    for (int it = 0; it < 2; ++it) {
        const int u  = tid + it * 256;      // 0..511
        const int r2 = u >> 2;              // tile row
        const int sg = (u & 3) ^ (r2 & 3);  // src segment (XOR swizzle)
        dstOff[it] = u * 8;
        srcOff[it] = (size_t)r2 * 1024 + sg * 8;
    }

    f32x4 acc[2][8];
    #pragma unroll
    for (int i = 0; i < 2; ++i)
        #pragma unroll
        for (int j = 0; j < 8; ++j)
            acc[i][j] = (f32x4){0.f, 0.f, 0.f, 0.f};

    #pragma unroll
    for (int it = 0; it < 2; ++it) {
        gload_lds16(aBase + srcOff[it], AsQ(0) + dstOff[it]);
        gload_lds16(bBase + srcOff[it], BsQ(0) + dstOff[it]);
    }

    for (int kt = 0; kt < 32; ++kt) {
        const int cur = kt & 1;
        __syncthreads();                      // tile kt ready; buf^1 free

        if (kt < 31) {                        // async-prefetch next K-tile
            const int k0n = (kt + 1) * 32;
            #pragma unroll
            for (int it = 0; it < 2; ++it) {
                gload_lds16(aBase + srcOff[it] + k0n, AsQ(cur ^ 1) + dstOff[it]);
                gload_lds16(bBase + srcOff[it] + k0n, BsQ(cur ^ 1) + dstOff[it]);
            }
        }

        const int sw = (g ^ (lc & 3)) << 3;
        bf16x8 af[2], bfr[8];
        #pragma unroll
        for (int i = 0; i < 2; ++i)
            af[i] = *(const bf16x8*)&AsQ(cur)[(w * 32 + i * 16 + lc) * 32 + sw];
        #pragma unroll
        for (int j = 0; j < 8; ++j)
            bfr[j] = *(const bf16x8*)&BsQ(cur)[(j * 16 + lc) * 32 + sw];

        #pragma unroll
        for (int i = 0; i < 2; ++i)
            #pragma unroll
            for (int j = 0; j < 8; ++j)
                acc[i][j] = __builtin_amdgcn_mfma_f32_16x16x32_bf16(af[i], bfr[j], acc[i][j], 0, 0, 0);
    }

    const int which = n0 >> 10;
    const int ncol0 = n0 & 1023;            // head-aligned (tile = one head)
    if (which < 2) {
        // ---- fused RMSNorm + RoPE + sqrt(qk_scale) for q / k ----
        unsigned short* outp = which == 0 ? oq : ok;
        float freq[4];
        #pragma unroll
        for (int j = 0; j < 4; ++j)
            freq[j] = __expf(-(float)(j * 16 + lc) * LN_BASE_64);

        #pragma unroll
        for (int i = 0; i < 2; ++i)
            #pragma unroll
            for (int r = 0; r < 4; ++r) {
                float s = 0.f;
                #pragma unroll
                for (int j = 0; j < 8; ++j) s += acc[i][j][r] * acc[i][j][r];
                #pragma unroll
                for (int off = 1; off < 16; off <<= 1) s += __shfl_xor(s, off);
                const float rms = rsqrtf(s * (1.0f / 128.0f) + NORM_EPS) * QK_MULT;

                const int trow = m0 + w * 32 + i * 16 + g * 4 + r;
                const float tpos = (float)(trow & (T_ - 1));
                unsigned short* op = outp + (size_t)trow * 1024 + ncol0;
                #pragma unroll
                for (int j = 0; j < 4; ++j) {
                    float sn, cs;
                    __sincosf(tpos * freq[j], &sn, &cs);
                    const float e = acc[i][j][r] * rms;       // even half
                    const float o = acc[i][j + 4][r] * rms;   // odd half (+64)
                    op[j * 16 + lc]      = f2bf(e * cs - o * sn);
                    op[j * 16 + lc + 64] = f2bf(e * sn + o * cs);
                }
            }
    } else {
        // V: transpose in LDS, then dump contiguous 256-B rows ->
        // vt[(b*8+h)*128 + d][t]. Full-line writes, no write-allocate RMW.
        const int b2 = m0 >> 11;
        const int hh = ncol0 >> 7;
        const int PAD = 136;                 // 272 B rows: 16-B aligned, odd*16
        __syncthreads();                     // staging reads done; reuse smem
        #pragma unroll
        for (int i = 0; i < 2; ++i) {
            const int t0 = w * 32 + i * 16 + g * 4;
            #pragma unroll
            for (int j = 0; j < 8; ++j) {
                uint2 val;
                val.x = pk2bf(acc[i][j][0], acc[i][j][1]);
                val.y = pk2bf(acc[i][j][2], acc[i][j][3]);
                *(uint2*)&smem[(j * 16 + lc) * PAD + t0] = val;
            }
        }
        __syncthreads();
        const int row  = tid >> 1;           // d (0..127)
        const int half = tid & 1;            // t half (64 shorts)
        const unsigned short* src = &smem[row * PAD + half * 64];
        unsigned short* dst = vt + ((size_t)(b2 * 8 + hh) * 128 + row) * T_
                                 + (m0 & 2047) + half * 64;
        #pragma unroll
        for (int it2 = 0; it2 < 8; ++it2)
            *(uint4*)(dst + it2 * 8) = *(const uint4*)(src + it2 * 8);
    }
    #undef AsQ
    #undef BsQ
}

// ---------------------------------------------------------------------------
// Output projection: C[4096x1024] fp32 = A * Bt^T. 128x64 tile (512 blocks,
// 3/CU, all resident), BK=64, async double-buffered staging + XOR swizzle.
// 2x2 waves of 64x32.
// ---------------------------------------------------------------------------
__global__ __launch_bounds__(256) void gemm_out(const unsigned short* __restrict__ A,
                                                const unsigned short* __restrict__ Bt,
                                                float* __restrict__ cf)
{
    __shared__ unsigned short As[2][128 * 64];   // 2 x 16 KB
    __shared__ unsigned short Bs[2][64 * 64];    // 2 x 8 KB  (48 KB total)

    const int tid  = threadIdx.x;
    const int lane = tid & 63;
    const int w    = tid >> 6;
    const int g    = lane >> 4;
    const int lc   = lane & 15;
    const int wm   = w >> 1;
    const int wn   = w & 1;

    const int m0 = blockIdx.y * 128;
    const int n0 = blockIdx.x * 64;

    const unsigned short* aBase = A  + (size_t)m0 * 1024;
    const unsigned short* bBase = Bt + (size_t)n0 * 1024;

    int dstA[4], dstB[2];
    size_t srcA[4], srcB[2];
    #pragma unroll
    for (int it = 0; it < 4; ++it) {
        const int u  = tid + it * 256;
        const int r2 = u >> 3;
        const int sg = (u & 7) ^ (r2 & 7);
        dstA[it] = u * 8;
        srcA[it] = (size_t)r2 * 1024 + sg * 8;
    }
    #pragma unroll
    for (int it = 0; it < 2; ++it) {
        const int u  = tid + it * 256;
        const int r2 = u >> 3;
        const int sg = (u & 7) ^ (r2 & 7);
        dstB[it] = u * 8;
        srcB[it] = (size_t)r2 * 1024 + sg * 8;
    }

    f32x4 acc[4][2];
    #pragma unroll
    for (int i = 0; i < 4; ++i)
        #pragma unroll
        for (int j = 0; j < 2; ++j)
            acc[i][j] = (f32x4){0.f, 0.f, 0.f, 0.f};

    #pragma unroll
    for (int it = 0; it < 4; ++it)
        gload_lds16(aBase + srcA[it], &As[0][dstA[it]]);
    #pragma unroll
    for (int it = 0; it < 2; ++it)
        gload_lds16(bBase + srcB[it], &Bs[0][dstB[it]]);

    for (int kt = 0; kt < 16; ++kt) {
        const int cur = kt & 1;
        __syncthreads();

        if (kt < 15) {
            const int k0n = (kt + 1) * 64;
            #pragma unroll
            for (int it = 0; it < 4; ++it)
                gload_lds16(aBase + srcA[it] + k0n, &As[cur ^ 1][dstA[it]]);
            #pragma unroll
            for (int it = 0; it < 2; ++it)
                gload_lds16(bBase + srcB[it] + k0n, &Bs[cur ^ 1][dstB[it]]);
        }

        #pragma unroll
        for (int dc = 0; dc < 2; ++dc) {
            const int sw = ((dc * 4 + g) ^ (lc & 7)) << 3;
            bf16x8 af[4], bfr[2];
            #pragma unroll
            for (int i = 0; i < 4; ++i)
                af[i] = *(const bf16x8*)&As[cur][(wm * 64 + i * 16 + lc) * 64 + sw];
            #pragma unroll
            for (int j = 0; j < 2; ++j)
                bfr[j] = *(const bf16x8*)&Bs[cur][(wn * 32 + j * 16 + lc) * 64 + sw];

            #pragma unroll
            for (int i = 0; i < 4; ++i)
                #pragma unroll
                for (int j = 0; j < 2; ++j)
                    acc[i][j] = __builtin_amdgcn_mfma_f32_16x16x32_bf16(af[i], bfr[j], acc[i][j], 0, 0, 0);
        }
    }

    #pragma unroll
    for (int i = 0; i < 4; ++i) {
        const int mrow = m0 + wm * 64 + i * 16 + g * 4;
        #pragma unroll
        for (int j = 0; j < 2; ++j) {
            const int nc = n0 + wn * 32 + j * 16 + lc;
            #pragma unroll
            for (int r = 0; r < 4; ++r)
                cf[(size_t)(mrow + r) * 1024 + nc] = acc[i][j][r];
        }
    }
}

// ---------------------------------------------------------------------------
// Flash attention v9 = v8 + __launch_bounds__(512, 2).
// R8 post-mortem: __launch_bounds__(512) with no min-waves arg let the
// compiler cap VGPR at 128 (4-waves/SIMD target) -> ~220 live regs spilled
// to scratch (WRITE_SIZE 8->37 MB, FETCH +7 MB, VGPR_Count 128). The
// (512, 2) form requests exactly our real occupancy (2 waves/EU = 8 waves
// = 1 block/CU, LDS-bound anyway) -> VGPR cap 256, no spill.
// Structure (unchanged): dual-group fused block. The 33-unit pair stream
// (tile qtA then qtB=31-qtA) is split at unit 17 across two 4-wave groups
// of one 512-thread block; 17 lockstep iterations every block; tile-B
// partials merge through LDS (in-block). 2 waves/SIMD hide each other's
// lgkm/MFMA chains. Each group: private 2x32 KB double buffer, stage-at-end
// + counted vmcnt(8) (1-iter DMA lead). XCD mapping: bid&7 -> 2 bh/XCD,
// L2-resident K/V. A-epilogue scratch rotated (d+row)&127; B-epilogue
// slabs stride-129.
// ---------------------------------------------------------------------------
__global__ __launch_bounds__(512, 2) void flash_attn(const unsigned short* __restrict__ qb,
                                                     const unsigned short* __restrict__ kb,
                                                     const unsigned short* __restrict__ vt,
                                                     unsigned short* __restrict__ o)
{
    // 2 groups x 2 bufs x (K 16KB | V 16KB) = 128 KB + 1 KB lscr
    __shared__ __align__(16) unsigned short smem[65536 + 512];
    float* lscrA = (float*)(smem + 65536);        // [64]
    float* lscrB = lscrA + 64;                    // [3][64]

    const int tid  = threadIdx.x;
    const int lane = tid & 63;
    const int w    = tid >> 6;          // 0..7
    const int g2   = w >> 2;            // stream group
    const int wj   = (w >> 1) & 1;      // j-half within group
    const int wq2  = w & 1;             // q-half
    const int qcol = lane & 31;
    const int hi   = lane >> 5;         // half-wave
    const int gtid = tid & 255;         // thread id within group

    // XCD-aware unit mapping: 256 blocks = 16 bh x 16 pairs
    const int bid = blockIdx.x;
    const int s   = bid >> 3;
    const int bh  = (bid & 7) + 8 * (s & 1);
    const int qtA = s >> 1;             // 0..15
    const int qtB = 31 - qtA;           // 16..31
    const int h   = bh & (H_ - 1);
    const int b   = bh >> 3;

    const size_t bhbase  = (size_t)b * T_ * HD + (size_t)h * 128;   // q,k,o
    const size_t bhvbase = (size_t)bh * 128 * T_;                   // vt

    int mI[4];
    size_t srcKoff[4], srcVoff[4];
    #pragma unroll
    for (int it = 0; it < 4; ++it) {
        const int m = (((gtid >> 6) * 4 + it)) * 64 + (gtid & 63);   // 0..1023
        mI[it] = m;
        const int jK = m >> 4, cK = (m & 15) ^ (jK & 15);
        srcKoff[it] = (size_t)jK * 1024 + cK * 8;
        const int dV = m >> 3, cV = (m & 7) ^ (dV & 7);
        srcVoff[it] = (size_t)dV * T_ + cV * 8;
    }
    const unsigned short* kgb = kb + bhbase;
    const unsigned short* vgb = vt + bhvbase;
    unsigned short* gbase = smem + g2 * 32768;    // group's 2-buffer region

    // stream position p -> KV unit (tile A: 0..qtA, then tile B: 0..qtB)
#define SRCU(p_) ((p_) > qtA ? (p_) - qtA - 1 : (p_))
#define STAGE(p_, l_) {                                                      \
        const size_t jo = (size_t)SRCU(p_) * 64;                             \
        unsigned short* Kd = gbase + ((l_) & 1) * 16384;                     \
        unsigned short* Vd = Kd + 8192;                                      \
        _Pragma("unroll")                                                    \
        for (int it = 0; it < 4; ++it)                                       \
            gload_lds16(kgb + jo * 1024 + srcKoff[it], &Kd[mI[it] * 8]);     \
        _Pragma("unroll")                                                    \
        for (int it = 0; it < 4; ++it)                                       \
            gload_lds16(vgb + jo + srcVoff[it], &Vd[mI[it] * 8]);            \
    }

    // Q frags: group0 starts on tile A, group1 on tile B
    bf16x8 qf[8];
    {
        const int qt0 = g2 ? qtB : qtA;
        const unsigned short* qp = qb + bhbase
            + (size_t)(qt0 * 64 + wq2 * 32 + qcol) * 1024 + hi * 8;
        #pragma unroll
        for (int ks = 0; ks < 8; ++ks)
            qf[ks] = *(const bf16x8*)(qp + ks * 16);
    }

    float lsum = 0.f;
    f32x16 otacc[4];
    #pragma unroll
    for (int dch = 0; dch < 4; ++dch)
        #pragma unroll
        for (int r = 0; r < 16; ++r) otacc[dch][r] = 0.f;

    // prologue: each group stages its local positions 0,1
    STAGE(g2 * 17 + 0, 0);
    STAGE(g2 ? 18 : 1, 1);

    for (int u = 0; u < 17; ++u) {
        // counted wait: drain own-group stage u (issued 1 iter ago);
        // stage u+1 (8 loads) stays in flight.
        if (u < 16) asm volatile("s_waitcnt vmcnt(8)" ::: "memory");
        else        asm volatile("s_waitcnt vmcnt(0)" ::: "memory");
        __builtin_amdgcn_s_barrier();           // all quarters of buf landed

        const int p = u + g2 * 17;              // stream position
        const bool livep = (p <= 32);
        const bool atD = (p == qtA) || (p == 32);
        if (livep && !(atD && (wj > wq2))) {
            unsigned short* Ks = gbase + (u & 1) * 16384;
            unsigned short* Vs = Ks + 8192;
            const int jrow = wj * 32 + qcol;

            // batch-issue operand reads (8 K-frags + 8 V-frags)
            bf16x8 kf[8], vf[8];
            #pragma unroll
            for (int ks = 0; ks < 8; ++ks) {
                const int c = ks * 2 + hi;
                kf[ks] = *(const bf16x8*)&Ks[(jrow * 16 + (c ^ (lane & 15))) * 8];
            }
            #pragma unroll
            for (int ks2 = 0; ks2 < 2; ++ks2)
                #pragma unroll
                for (int dch = 0; dch < 4; ++dch) {
                    const int c = wj * 4 + ks2 * 2 + hi;
                    const int drow = dch * 32 + qcol;
                    vf[ks2 * 4 + dch] = *(const bf16x8*)&Vs[(drow * 8 + (c ^ (lane & 7))) * 8];
                }

            // ---- S^T = K Q^T : two parallel accumulation chains ----
            f32x16 sacc0, sacc1;
            #pragma unroll
            for (int r = 0; r < 16; ++r) { sacc0[r] = 0.f; sacc1[r] = 0.f; }
            __builtin_amdgcn_s_setprio(1);
            #pragma unroll
            for (int ks = 0; ks < 8; ks += 2) {
                sacc0 = __builtin_amdgcn_mfma_f32_32x32x16_bf16(kf[ks], qf[ks], sacc0, 0, 0, 0);
                sacc1 = __builtin_amdgcn_mfma_f32_32x32x16_bf16(kf[ks + 1], qf[ks + 1], sacc1, 0, 0, 0);
            }
            __builtin_amdgcn_s_setprio(0);
            f32x16 sacc = sacc0 + sacc1;

            if (atD && wj == wq2) {              // diagonal 32x32 mask
                #pragma unroll
                for (int r = 0; r < 16; ++r) {
                    const int jl = (r & 3) + 8 * (r >> 2) + 4 * hi;
                    if (qcol < jl) sacc[r] = -1e30f;
                }
            }

            unsigned int dw[8];
            #pragma unroll
            for (int m2 = 0; m2 < 8; ++m2) {
                const float p0 = __expf(sacc[2 * m2]);
                const float p1 = __expf(sacc[2 * m2 + 1]);
                lsum += p0 + p1;
                dw[m2] = pk2bf(p0, p1);
            }

            // P^T C-layout -> PV B-frags via permlane32_swap
            __builtin_amdgcn_s_setprio(1);
            #pragma unroll
            for (int ks2 = 0; ks2 < 2; ++ks2) {
                const uint32x2 s02 = __builtin_amdgcn_permlane32_swap(
                    dw[4 * ks2 + 0], dw[4 * ks2 + 2], 0, 0);
                const uint32x2 s13 = __builtin_amdgcn_permlane32_swap(
                    dw[4 * ks2 + 1], dw[4 * ks2 + 3], 0, 0);
                union { unsigned int u2[4]; bf16x8 v; } pf;
                pf.u2[0] = s02[0];
                pf.u2[1] = s13[0];
                pf.u2[2] = s02[1];
                pf.u2[3] = s13[1];
                #pragma unroll
                for (int dch = 0; dch < 4; ++dch)
                    otacc[dch] = __builtin_amdgcn_mfma_f32_32x32x16_bf16(vf[ks2 * 4 + dch], pf.v, otacc[dch], 0, 0, 0);
            }
            __builtin_amdgcn_s_setprio(0);
        }

        if (u == qtA) {
            // ---- tile A epilogue (group0-internal; block-uniform u so all
            // 8 waves pass the barriers). Scratch = group0's freed buffer.
            float* scrA = (float*)(smem + (qtA & 1) * 16384);   // 32 KB
            float lsA = 0.f;
            if (g2 == 0) { lsA = lsum + __shfl_xor(lsum, 32); }
            asm volatile("s_waitcnt lgkmcnt(0)" ::: "memory");
            __builtin_amdgcn_s_barrier();
            const int row = wq2 * 32 + qcol;
            if (g2 == 0 && wj == 1) {
                float* s0 = scrA + (size_t)row * 128;
                #pragma unroll
                for (int dch = 0; dch < 4; ++dch)
                    #pragma unroll
                    for (int r = 0; r < 16; ++r) {
                        const int d = dch * 32 + (r & 3) + 8 * (r >> 2) + 4 * hi;
                        s0[(d + row) & 127] = otacc[dch][r];   // rotation: conflict-free
                    }
                if (hi == 0) lscrA[row] = lsA;
            }
            asm volatile("s_waitcnt lgkmcnt(0)" ::: "memory");
            __builtin_amdgcn_s_barrier();
            if (g2 == 0) {
                if (wj == 0) {
                    const float l = lsA + lscrA[row];
                    const float inv = 1.0f / l;
                    const float* s0 = scrA + (size_t)row * 128;
                    unsigned short* op = o + bhbase + (size_t)(qtA * 64 + row) * 1024;
                    #pragma unroll
                    for (int dch = 0; dch < 4; ++dch)
                        #pragma unroll
                        for (int k4 = 0; k4 < 4; ++k4) {
                            const int d0 = dch * 32 + 8 * k4 + 4 * hi;
                            const float f0 = (otacc[dch][4 * k4 + 0] + s0[(d0 + 0 + row) & 127]) * inv;
                            const float f1 = (otacc[dch][4 * k4 + 1] + s0[(d0 + 1 + row) & 127]) * inv;
                            const float f2 = (otacc[dch][4 * k4 + 2] + s0[(d0 + 2 + row) & 127]) * inv;
                            const float f3 = (otacc[dch][4 * k4 + 3] + s0[(d0 + 3 + row) & 127]) * inv;
                            uint2 val;
                            val.x = pk2bf(f0, f1);
                            val.y = pk2bf(f2, f3);
                            *(uint2*)(op + d0) = val;
                        }
                }
                // reset accumulators; switch to tile B
                lsum = 0.f;
                #pragma unroll
                for (int dch = 0; dch < 4; ++dch)
                    #pragma unroll
                    for (int r = 0; r < 16; ++r) otacc[dch][r] = 0.f;
                const unsigned short* qp = qb + bhbase
                    + (size_t)(qtB * 64 + wq2 * 32 + qcol) * 1024 + hi * 8;
                #pragma unroll
                for (int ks = 0; ks < 8; ++ks)
                    qf[ks] = *(const bf16x8*)(qp + ks * 16);
            }
        }

        __builtin_amdgcn_s_barrier();       // all reads of buf (u&1) done
        const int ln = u + 2;
        if (ln <= 16) {
            // group1 position capped at 32: ln==16 stages a harmless dummy
            // (re-stage of pos 32) into a buffer that is never read again.
            const int pp = g2 ? (ln + 17 > 32 ? 32 : ln + 17) : ln;
            STAGE(pp, ln);
        }
    }

    // ---- tile B epilogue: merge 4 partials (2 groups x 2 wj) via LDS ----
    {
        lsum += __shfl_xor(lsum, 32);
        asm volatile("s_waitcnt lgkmcnt(0)" ::: "memory");
        __builtin_amdgcn_s_barrier();
        const int row  = wq2 * 32 + qcol;
        const int slab = g2 * 2 + wj;               // 0..3; 0 = reader
        float* scrB = (float*)smem;                 // [3][64][129] f32 = 99 KB
        if (slab > 0) {
            float* s0 = scrB + (size_t)(slab - 1) * (64 * 129) + (size_t)row * 129;
            #pragma unroll
            for (int dch = 0; dch < 4; ++dch)
                #pragma unroll
                for (int r = 0; r < 16; ++r)
                    s0[dch * 32 + (r & 3) + 8 * (r >> 2) + 4 * hi] = otacc[dch][r];
            if (hi == 0) lscrB[(slab - 1) * 64 + row] = lsum;
        }
        asm volatile("s_waitcnt lgkmcnt(0)" ::: "memory");
        __builtin_amdgcn_s_barrier();
        if (slab == 0) {
            const float l = lsum + lscrB[row] + lscrB[64 + row] + lscrB[128 + row];
            const float inv = 1.0f / l;
            const float* s1 = scrB + (size_t)row * 129;
            const float* s2 = s1 + 64 * 129;
            const float* s3 = s2 + 64 * 129;
            unsigned short* op = o + bhbase + (size_t)(qtB * 64 + row) * 1024;
            #pragma unroll
            for (int dch = 0; dch < 4; ++dch)
                #pragma unroll
                for (int k4 = 0; k4 < 4; ++k4) {
                    const int d0 = dch * 32 + 8 * k4 + 4 * hi;
                    float f[4];
                    #pragma unroll
                    for (int i = 0; i < 4; ++i)
                        f[i] = (otacc[dch][4 * k4 + i] + s1[d0 + i] + s2[d0 + i] + s3[d0 + i]) * inv;
                    uint2 val;
                    val.x = pk2bf(f[0], f[1]);
                    val.y = pk2bf(f[2], f[3]);
                    *(uint2*)(op + d0) = val;
                }
        }
    }
#undef STAGE
#undef SRCU
}

// ---------------------------------------------------------------------------
extern "C" void kernel_launch(void* const* d_in, const int* in_sizes, int n_in,
                              void* d_out, int out_size, void* d_ws, size_t ws_size,
                              hipStream_t stream)
{
    const float* x  = (const float*)d_in[0];
    const float* wq = (const float*)d_in[1];
    const float* wk = (const float*)d_in[2];
    const float* wv = (const float*)d_in[3];
    const float* wo = (const float*)d_in[4];
    float* out = (float*)d_out;

    const size_t SZ = (size_t)NROW * HD;               // 4M elements
    unsigned short* qb    = (unsigned short*)d_ws;     // 8 MB
    unsigned short* kb    = qb + SZ;                   // 8 MB
    unsigned short* vt    = kb + SZ;                   // 8 MB [(b,h),d,t]
    unsigned short* ob    = vt + SZ;                   // 8 MB
    unsigned short* xb    = ob + SZ;                   // 8 MB
    unsigned short* wqkvT = xb + SZ;                   // 6 MB [3072][1024]
    unsigned short* woT   = wqkvT + 3 * 1024 * 1024;   // 2 MB

    // prologue: x cast + 4 weight transposes, one launch
    prep<<<dim3(32, 32, 5), 256, 0, stream>>>(x, wq, wk, wv, wo, xb, wqkvT, woT);

    // fused QKV projection (+ RMSNorm/RoPE on q,k; V written transposed)
    gemm_qkv<<<dim3(24, 32), 256, 0, stream>>>(xb, wqkvT, qb, kb, vt);

    // dual-group paired flash attention: 256 blocks x 512 thr, 17 iters each
    flash_attn<<<dim3(256), 512, 0, stream>>>(qb, kb, vt, ob);

    // output projection, 128x64 tiles -> 512 blocks
    gemm_out<<<dim3(16, 32), 256, 0, stream>>>(ob, woT, out);
}